// Round 2
// baseline (997.721 us; speedup 1.0000x reference)
//
#include <hip/hip_runtime.h>
#include <hip/hip_bf16.h>

// RelAttention (Transformer-XL style) on MI355X.
// Inputs/outputs fp32 (per reference dtypes); internal compute bf16 MFMA w/
// fp32 accum; workspace intermediates bf16.
// B=4, S=1024, D=1024, H=16, DH=64, BH=64. SCALE = 1/32.

typedef __bf16 bf16x8 __attribute__((ext_vector_type(8)));
typedef float  f32x4  __attribute__((ext_vector_type(4)));

struct alignas(16) U128 { unsigned long long lo, hi; };

__device__ __forceinline__ bf16x8 ldg8(const __hip_bfloat16* p) {
    U128 u = *reinterpret_cast<const U128*>(p);
    return __builtin_bit_cast(bf16x8, u);
}

__device__ __forceinline__ __bf16 f2b(float f) {
    __hip_bfloat16 h = __float2bfloat16(f);
    return __builtin_bit_cast(__bf16, h);
}

// load 8 consecutive fp32, round to bf16x8 fragment
__device__ __forceinline__ bf16x8 ldg8cvt(const float* p) {
    f32x4 a = *reinterpret_cast<const f32x4*>(p);
    f32x4 b = *reinterpret_cast<const f32x4*>(p + 4);
    bf16x8 r;
    r[0] = f2b(a[0]); r[1] = f2b(a[1]); r[2] = f2b(a[2]); r[3] = f2b(a[3]);
    r[4] = f2b(b[0]); r[5] = f2b(b[1]); r[6] = f2b(b[2]); r[7] = f2b(b[3]);
    return r;
}

#define MFMA16(a, b, c) __builtin_amdgcn_mfma_f32_16x16x32_bf16((a), (b), (c), 0, 0, 0)

// ---------------------------------------------------------------------------
// GEMM: C[m][n] = sum_k A[m][k] * W[n][k] + bias[n]   (A:[4096,1024], W:[1024,1024])
// A32: A is fp32 (else bf16 ws tensor). W/bias/u/v always fp32 (harness inputs).
// MODE 0: out0 = bf16(C + u[n&63]), out1 = bf16(C + v[n&63])          (Q path)
// MODE 1: out0 = C token-major [m][n]; fp32 if OUT32 else bf16        (K / final)
// MODE 2: out0 = bf16(C) head-transposed Vt[(b*16+h)*64+d][s]         (V path)
// ---------------------------------------------------------------------------
template <int MODE, bool A32, bool OUT32>
__global__ __launch_bounds__(256) void gemm16(
    const void* __restrict__ Av,
    const float* __restrict__ W,
    const float* __restrict__ bias,
    const float* __restrict__ uvec,
    const float* __restrict__ vvec,
    void* __restrict__ out0v,
    __hip_bfloat16* __restrict__ out1)
{
    const int lane = threadIdx.x & 63;
    const int wv   = threadIdx.x >> 6;
    const int quad = lane >> 4, c16 = lane & 15;
    const int m0 = blockIdx.y * 64 + wv * 16;  // this wave's 16 rows
    const int n0 = blockIdx.x * 64;            // block's 64 cols

    f32x4 acc[4];
    #pragma unroll
    for (int t = 0; t < 4; ++t) acc[t] = (f32x4){0.f, 0.f, 0.f, 0.f};

    const size_t aoff = (size_t)(m0 + c16) * 1024 + quad * 8;
    const float* apf = (const float*)Av + aoff;
    const __hip_bfloat16* apb = (const __hip_bfloat16*)Av + aoff;
    const float* wp = W + (size_t)(n0 + c16) * 1024 + quad * 8;

    #pragma unroll 4
    for (int k0 = 0; k0 < 1024; k0 += 32) {
        bf16x8 a = A32 ? ldg8cvt(apf + k0) : ldg8(apb + k0);
        acc[0] = MFMA16(a, ldg8cvt(wp + k0),             acc[0]);
        acc[1] = MFMA16(a, ldg8cvt(wp + 16 * 1024 + k0), acc[1]);
        acc[2] = MFMA16(a, ldg8cvt(wp + 32 * 1024 + k0), acc[2]);
        acc[3] = MFMA16(a, ldg8cvt(wp + 48 * 1024 + k0), acc[3]);
    }

    #pragma unroll
    for (int t = 0; t < 4; ++t) {
        #pragma unroll
        for (int r = 0; r < 4; ++r) {
            const int m = m0 + quad * 4 + r;        // C/D: row = quad*4+reg
            const int n = n0 + t * 16 + c16;        //      col = lane&15
            float val = acc[t][r] + bias[n];
            if (MODE == 0) {
                __hip_bfloat16* o0 = (__hip_bfloat16*)out0v;
                o0  [(size_t)m * 1024 + n] = __float2bfloat16(val + uvec[n & 63]);
                out1[(size_t)m * 1024 + n] = __float2bfloat16(val + vvec[n & 63]);
            } else if (MODE == 1) {
                if (OUT32) ((float*)out0v)[(size_t)m * 1024 + n] = val;
                else ((__hip_bfloat16*)out0v)[(size_t)m * 1024 + n] =
                         __float2bfloat16(val);
            } else {
                const int bb = m >> 10, s = m & 1023, hh = n >> 6, d = n & 63;
                ((__hip_bfloat16*)out0v)[((size_t)((bb * 16 + hh) * 64 + d) << 10) + s] =
                    __float2bfloat16(val);
            }
        }
    }
}

// ---------------------------------------------------------------------------
// Fused relative attention. Block = (head bh, row tile i0..i0+15), 256 thr.
// LDS: logits tile [16][1024] fp32 = 64 KiB, XOR-swizzled in 16B chunks.
// ---------------------------------------------------------------------------
__device__ __forceinline__ int lidx(int row, int c) {
    return (row << 10) + ((((c >> 2) ^ row) << 2) | (c & 3));
}

__global__ __launch_bounds__(256) void attn_kernel(
    const __hip_bfloat16* __restrict__ Qu,   // [4096][1024] token-major (q+u), bf16
    const __hip_bfloat16* __restrict__ Qv,   // [4096][1024] token-major (q+v), bf16
    const __hip_bfloat16* __restrict__ Kb,   // [4096][1024] token-major, bf16
    const float*          __restrict__ Pos,  // [4096][1024] token-major, fp32 input
    const __hip_bfloat16* __restrict__ Vt,   // [bh*64+d][s] head-transposed V, bf16
    __hip_bfloat16* __restrict__ O)          // [4096][1024] token-major, bf16
{
    __shared__ float Ls[16 * 1024];

    const int tid  = threadIdx.x;
    const int lane = tid & 63, wv = tid >> 6;
    const int quad = lane >> 4, c16 = lane & 15;
    const int i0 = blockIdx.x * 16;
    const int bh = blockIdx.y;
    const int b = bh >> 4, h = bh & 15;
    const size_t headoff = (size_t)h * 64;
    const size_t tokbase = (size_t)b * 1024;

    // Phase 1: the rel-shift leaves exactly one zero per row, at c = i+1.
    if (tid < 16) {
        const int i = i0 + tid;
        if (i + 1 < 1024) Ls[lidx(tid, i + 1)] = 0.f;
    }

    // Phase 2: BD_raw = (q+v)·r^T via MFMA, scattered through the rel-shift.
    // bd_raw row j, col l  ->  out row j   at c = l+j-1023  (l >= 1023-j)
    //                      ->  out row j-1 at c = l+j+1     (l <= 1022-j)
    {
        const __hip_bfloat16* qvp =
            Qv + (tokbase + i0 + c16) * 1024 + headoff + quad * 8;
        const bf16x8 a0 = ldg8(qvp);
        const bf16x8 a1 = ldg8(qvp + 32);
        for (int t = 0; t < 16; ++t) {
            const int l0 = wv * 256 + t * 16;
            const float* rp =
                Pos + (tokbase + l0 + c16) * 1024 + headoff + quad * 8;
            f32x4 c = (f32x4){0.f, 0.f, 0.f, 0.f};
            c = MFMA16(a0, ldg8cvt(rp), c);
            c = MFMA16(a1, ldg8cvt(rp + 32), c);
            const int l = l0 + c16;
            #pragma unroll
            for (int r = 0; r < 4; ++r) {
                const int jl = quad * 4 + r;   // local bd_raw row
                const int j  = i0 + jl;
                const float val = c[r];
                if (l >= 1023 - j) Ls[lidx(jl, l + j - 1023)] = val;
                if (jl >= 1 && l <= 1022 - j) Ls[lidx(jl - 1, l + j + 1)] = val;
            }
        }
    }

    // Phase 3: extra bd_raw row j2 = i0+16 feeds out row 15 at c >= i0+17.
    {
        const int j2 = i0 + 16;
        if (j2 < 1024) {
            const __hip_bfloat16* q2 = Qv + (tokbase + j2) * 1024 + headoff;
            for (int c = i0 + 17 + tid; c < 1024; c += 256) {
                const int l = c - i0 - 17;
                const float* rp = Pos + (tokbase + l) * 1024 + headoff;
                float s = 0.f;
                for (int d = 0; d < 64; ++d)
                    s += __bfloat162float(q2[d]) * rp[d];
                Ls[lidx(15, c)] = s;
            }
        }
    }
    __syncthreads();

    // Phase 4: AC = (q+u)·k^T via MFMA; fuse L = (L + ac) * SCALE.
    {
        const __hip_bfloat16* qup =
            Qu + (tokbase + i0 + c16) * 1024 + headoff + quad * 8;
        const bf16x8 a0 = ldg8(qup);
        const bf16x8 a1 = ldg8(qup + 32);
        for (int t = 0; t < 16; ++t) {
            const int c0 = wv * 256 + t * 16;
            const __hip_bfloat16* kp =
                Kb + (tokbase + c0 + c16) * 1024 + headoff + quad * 8;
            f32x4 c = (f32x4){0.f, 0.f, 0.f, 0.f};
            c = MFMA16(a0, ldg8(kp), c);
            c = MFMA16(a1, ldg8(kp + 32), c);
            const int cc = c0 + c16;
            #pragma unroll
            for (int r = 0; r < 4; ++r) {
                const int il = quad * 4 + r;
                const int idx = lidx(il, cc);
                Ls[idx] = (Ls[idx] + c[r]) * 0.03125f;
            }
        }
    }
    __syncthreads();

    // Phase 5: row softmax, normalized in place (wave wv owns rows 4wv..4wv+3).
    for (int rr = 0; rr < 4; ++rr) {
        const int row = wv * 4 + rr;
        float x[16];
        float m = -3.4e38f;
        #pragma unroll
        for (int k = 0; k < 16; ++k) {
            x[k] = Ls[lidx(row, k * 64 + lane)];
            m = fmaxf(m, x[k]);
        }
        #pragma unroll
        for (int off = 32; off > 0; off >>= 1) m = fmaxf(m, __shfl_xor(m, off));
        float s = 0.f;
        #pragma unroll
        for (int k = 0; k < 16; ++k) { x[k] = __expf(x[k] - m); s += x[k]; }
        #pragma unroll
        for (int off = 32; off > 0; off >>= 1) s += __shfl_xor(s, off);
        const float rinv = 1.f / s;
        #pragma unroll
        for (int k = 0; k < 16; ++k) Ls[lidx(row, k * 64 + lane)] = x[k] * rinv;
    }
    __syncthreads();

    // Phase 6: O_tile = P @ V  (wave wv owns output d-tile d0 = wv*16).
    {
        const int d0 = wv * 16;
        const __hip_bfloat16* vp =
            Vt + ((size_t)bh * 64 + d0 + c16) * 1024 + quad * 8;
        f32x4 acc = (f32x4){0.f, 0.f, 0.f, 0.f};
        for (int kk = 0; kk < 1024; kk += 32) {
            const f32x4 f0 = *(const f32x4*)&Ls[lidx(c16, kk + quad * 8)];
            const f32x4 f1 = *(const f32x4*)&Ls[lidx(c16, kk + quad * 8 + 4)];
            bf16x8 a;
            a[0] = f2b(f0[0]); a[1] = f2b(f0[1]); a[2] = f2b(f0[2]); a[3] = f2b(f0[3]);
            a[4] = f2b(f1[0]); a[5] = f2b(f1[1]); a[6] = f2b(f1[2]); a[7] = f2b(f1[3]);
            acc = MFMA16(a, ldg8(vp + kk), acc);
        }
        #pragma unroll
        for (int r = 0; r < 4; ++r) {
            const int i = i0 + quad * 4 + r;
            const int d = d0 + c16;
            O[(tokbase + i) * 1024 + headoff + d] = __float2bfloat16(acc[r]);
        }
    }
}

// ---------------------------------------------------------------------------
extern "C" void kernel_launch(void* const* d_in, const int* in_sizes, int n_in,
                              void* d_out, int out_size, void* d_ws, size_t ws_size,
                              hipStream_t stream)
{
    const float* x   = (const float*)d_in[0];
    const float* u   = (const float*)d_in[1];
    const float* v   = (const float*)d_in[2];
    const float* pos = (const float*)d_in[3];
    const float* Wq  = (const float*)d_in[4];
    const float* bq  = (const float*)d_in[5];
    const float* Wk  = (const float*)d_in[6];
    const float* bk  = (const float*)d_in[7];
    const float* Wv  = (const float*)d_in[8];
    const float* bv  = (const float*)d_in[9];
    const float* Wc  = (const float*)d_in[10];
    const float* bc  = (const float*)d_in[11];

    const size_t BUF = (size_t)4096 * 1024 * sizeof(__hip_bfloat16);  // 8 MiB
    char* ws = (char*)d_ws;
    __hip_bfloat16* Qu = (__hip_bfloat16*)(ws + 0 * BUF);
    __hip_bfloat16* Qv = (__hip_bfloat16*)(ws + 1 * BUF);
    __hip_bfloat16* Kb = (__hip_bfloat16*)(ws + 2 * BUF);
    __hip_bfloat16* Vt = (__hip_bfloat16*)(ws + 3 * BUF);
    __hip_bfloat16* O  = (__hip_bfloat16*)(ws + 4 * BUF);

    const dim3 ggrid(16, 64), gblk(256);
    gemm16<0, true, false><<<ggrid, gblk, 0, stream>>>(x, Wq, bq, u, v, Qu, Qv);
    gemm16<1, true, false><<<ggrid, gblk, 0, stream>>>(x, Wk, bk, nullptr, nullptr,
                                                       Kb, nullptr);
    gemm16<2, true, false><<<ggrid, gblk, 0, stream>>>(x, Wv, bv, nullptr, nullptr,
                                                       Vt, nullptr);
    attn_kernel<<<dim3(64, 64), gblk, 0, stream>>>(Qu, Qv, Kb, pos, Vt, O);
    gemm16<1, false, true><<<ggrid, gblk, 0, stream>>>(O, Wc, bc, nullptr, nullptr,
                                                       d_out, nullptr);
}

// Round 3
// 508.442 us; speedup vs baseline: 1.9623x; 1.9623x over previous
//
#include <hip/hip_runtime.h>
#include <hip/hip_bf16.h>

// RelAttention (Transformer-XL style) on MI355X.
// fp32 in/out; internal bf16 MFMA w/ fp32 accum.
// B=4, S=1024, D=1024, H=16, DH=64, BH=64. SCALE = 1/32.
//
// Pipeline: cvt (fp32->bf16 x + weights) -> fused QKV GEMM (m97-style LDS
// staging, 128x128 tile) -> fused rel-attention -> final GEMM.

typedef __bf16 bf16x8 __attribute__((ext_vector_type(8)));
typedef float  f32x4  __attribute__((ext_vector_type(4)));
typedef unsigned short u16x4 __attribute__((ext_vector_type(4)));

struct alignas(16) U128 { unsigned long long lo, hi; };

__device__ __forceinline__ bf16x8 ldg8(const __hip_bfloat16* p) {
    U128 u = *reinterpret_cast<const U128*>(p);
    return __builtin_bit_cast(bf16x8, u);
}

__device__ __forceinline__ __bf16 f2b(float f) {
    __hip_bfloat16 h = __float2bfloat16(f);
    return __builtin_bit_cast(__bf16, h);
}
__device__ __forceinline__ unsigned short f2bu(float f) {
    __hip_bfloat16 h = __float2bfloat16(f);
    return __builtin_bit_cast(unsigned short, h);
}

__device__ __forceinline__ bf16x8 ldg8cvt(const float* p) {
    f32x4 a = *reinterpret_cast<const f32x4*>(p);
    f32x4 b = *reinterpret_cast<const f32x4*>(p + 4);
    bf16x8 r;
    r[0] = f2b(a[0]); r[1] = f2b(a[1]); r[2] = f2b(a[2]); r[3] = f2b(a[3]);
    r[4] = f2b(b[0]); r[5] = f2b(b[1]); r[6] = f2b(b[2]); r[7] = f2b(b[3]);
    return r;
}

#define MFMA16(a, b, c) __builtin_amdgcn_mfma_f32_16x16x32_bf16((a), (b), (c), 0, 0, 0)

// async global->LDS, 16B per lane; lds dest must be wave-uniform base.
__device__ __forceinline__ void gll16(const __hip_bfloat16* g, void* lds_wave_base) {
    __builtin_amdgcn_global_load_lds(
        (const __attribute__((address_space(1))) void*)g,
        (__attribute__((address_space(3))) void*)lds_wave_base,
        16, 0, 0);
}

// ---------------------------------------------------------------------------
// fp32 -> bf16 conversion: x (4M), Wq,Wk,Wv (1M each, stacked), Wc (1M).
// 8M elements total, 8 per thread -> 4096 blocks x 256.
// ---------------------------------------------------------------------------
__global__ __launch_bounds__(256) void cvt_kernel(
    const float* __restrict__ x,  const float* __restrict__ wq,
    const float* __restrict__ wk, const float* __restrict__ wv,
    const float* __restrict__ wc,
    __hip_bfloat16* __restrict__ xb, __hip_bfloat16* __restrict__ wqkvb,
    __hip_bfloat16* __restrict__ wcb)
{
    const size_t base = ((size_t)blockIdx.x * 256 + threadIdx.x) * 8;
    const size_t M4 = (size_t)4 << 20, M1 = (size_t)1 << 20;
    const float* src; __hip_bfloat16* dst; size_t o;
    if (base < M4)              { src = x;  dst = xb;           o = base; }
    else if (base < M4 + M1)    { src = wq; dst = wqkvb;        o = base - M4; }
    else if (base < M4 + 2*M1)  { src = wk; dst = wqkvb + M1;   o = base - M4 - M1; }
    else if (base < M4 + 3*M1)  { src = wv; dst = wqkvb + 2*M1; o = base - M4 - 2*M1; }
    else                        { src = wc; dst = wcb;          o = base - M4 - 3*M1; }
    *(bf16x8*)(dst + o) = ldg8cvt(src + o);
}

// ---------------------------------------------------------------------------
// m97-style GEMM: C[m][n] = sum_k A[m][k]*Bm[n][k] (+ epilogue), K=1024.
// 128x128 tile, BK=32, 4 waves in 2x2, each wave 64x64 (4x4 16x16x32 MFMAs).
// MODE 0 (QKV): Bm=[3072][1024]; n-block <8 -> Qu/Qv (+bq,+u/+v),
//               <16 -> Kb (+bk), else Vt head-transposed (+bv).
// MODE 1 (final): Bm=[1024][1024]; dout fp32 = C + bc[n].
// ---------------------------------------------------------------------------
template <int MODE>
__global__ __launch_bounds__(256) void gemm_lds(
    const __hip_bfloat16* __restrict__ A,
    const __hip_bfloat16* __restrict__ Bm,
    const float* __restrict__ bq, const float* __restrict__ bk,
    const float* __restrict__ bv, const float* __restrict__ u,
    const float* __restrict__ v,
    __hip_bfloat16* __restrict__ Qu, __hip_bfloat16* __restrict__ Qv,
    __hip_bfloat16* __restrict__ Kb, __hip_bfloat16* __restrict__ Vt,
    float* __restrict__ dout, const float* __restrict__ bc)
{
    __shared__ __hip_bfloat16 As[128 * 32];
    __shared__ __hip_bfloat16 Bs[128 * 32];

    const int tid  = threadIdx.x;
    const int lane = tid & 63, w = tid >> 6;
    const int quad = lane >> 4, c16 = lane & 15;
    const int wm = w >> 1, wn = w & 1;
    const int m0 = blockIdx.y * 128;
    const int n0 = blockIdx.x * 128;

    // staging: chunk c = w*64+lane (batch 0) and +256 (batch 1);
    // row = c>>2, col8 = (c&3)*8; LDS byte offset = c*16.
    const int srow = w * 16 + (lane >> 2);
    const int scol = (lane & 3) * 8;
    const __hip_bfloat16* gA0 = A  + (size_t)(m0 + srow) * 1024 + scol;
    const __hip_bfloat16* gA1 = gA0 + (size_t)64 * 1024;
    const __hip_bfloat16* gB0 = Bm + (size_t)(n0 + srow) * 1024 + scol;
    const __hip_bfloat16* gB1 = gB0 + (size_t)64 * 1024;
    char* ldsA0 = (char*)As + (w << 10);
    char* ldsA1 = ldsA0 + 4096;
    char* ldsB0 = (char*)Bs + (w << 10);
    char* ldsB1 = ldsB0 + 4096;

    f32x4 acc[4][4] = {};

    for (int k0 = 0; k0 < 1024; k0 += 32) {
        gll16(gA0 + k0, ldsA0);
        gll16(gA1 + k0, ldsA1);
        gll16(gB0 + k0, ldsB0);
        gll16(gB1 + k0, ldsB1);
        __syncthreads();   // drains vmcnt -> staged data visible

        bf16x8 af[4], bfr[4];
        #pragma unroll
        for (int i = 0; i < 4; ++i) {
            af[i]  = *(const bf16x8*)&As[(wm * 64 + i * 16 + c16) * 32 + quad * 8];
            bfr[i] = *(const bf16x8*)&Bs[(wn * 64 + i * 16 + c16) * 32 + quad * 8];
        }
        #pragma unroll
        for (int mi = 0; mi < 4; ++mi)
            #pragma unroll
            for (int ni = 0; ni < 4; ++ni)
                acc[mi][ni] = MFMA16(af[mi], bfr[ni], acc[mi][ni]);
        __syncthreads();   // reads done before next iteration overwrites
    }

    #pragma unroll
    for (int mi = 0; mi < 4; ++mi) {
        #pragma unroll
        for (int ni = 0; ni < 4; ++ni) {
            const int m = m0 + wm * 64 + mi * 16 + quad * 4;  // +r
            const int n = n0 + wn * 64 + ni * 16 + c16;
            if (MODE == 0) {
                if (n < 1024) {
                    const float b0 = bq[n], uu = u[n & 63], vv = v[n & 63];
                    #pragma unroll
                    for (int r = 0; r < 4; ++r) {
                        const float val = acc[mi][ni][r] + b0;
                        Qu[(size_t)(m + r) * 1024 + n] = __float2bfloat16(val + uu);
                        Qv[(size_t)(m + r) * 1024 + n] = __float2bfloat16(val + vv);
                    }
                } else if (n < 2048) {
                    const int nn = n - 1024;
                    const float b0 = bk[nn];
                    #pragma unroll
                    for (int r = 0; r < 4; ++r)
                        Kb[(size_t)(m + r) * 1024 + nn] =
                            __float2bfloat16(acc[mi][ni][r] + b0);
                } else {
                    const int nn = n - 2048;
                    const float b0 = bv[nn];
                    const int d = nn & 63, hh = nn >> 6;
                    const int bb = m >> 10, s = m & 1023;
                    u16x4 pk;
                    #pragma unroll
                    for (int r = 0; r < 4; ++r)
                        pk[r] = f2bu(acc[mi][ni][r] + b0);
                    *(u16x4*)&Vt[(((size_t)(bb * 16 + hh) * 64 + d) << 10) + s] = pk;
                }
            } else {
                const float b0 = bc[n];
                #pragma unroll
                for (int r = 0; r < 4; ++r)
                    dout[(size_t)(m + r) * 1024 + n] = acc[mi][ni][r] + b0;
            }
        }
    }
}

// ---------------------------------------------------------------------------
// Fused relative attention (unchanged from round 2).
// Block = (head bh, row tile i0..i0+15), 256 thr, 64 KiB LDS logits tile.
// ---------------------------------------------------------------------------
__device__ __forceinline__ int lidx(int row, int c) {
    return (row << 10) + ((((c >> 2) ^ row) << 2) | (c & 3));
}

__global__ __launch_bounds__(256) void attn_kernel(
    const __hip_bfloat16* __restrict__ Qu,
    const __hip_bfloat16* __restrict__ Qv,
    const __hip_bfloat16* __restrict__ Kb,
    const float*          __restrict__ Pos,
    const __hip_bfloat16* __restrict__ Vt,
    __hip_bfloat16* __restrict__ O)
{
    __shared__ float Ls[16 * 1024];

    const int tid  = threadIdx.x;
    const int lane = tid & 63, wv = tid >> 6;
    const int quad = lane >> 4, c16 = lane & 15;
    const int i0 = blockIdx.x * 16;
    const int bh = blockIdx.y;
    const int b = bh >> 4, h = bh & 15;
    const size_t headoff = (size_t)h * 64;
    const size_t tokbase = (size_t)b * 1024;

    if (tid < 16) {
        const int i = i0 + tid;
        if (i + 1 < 1024) Ls[lidx(tid, i + 1)] = 0.f;
    }

    // BD_raw = (q+v)·r^T, scattered through the rel-shift.
    {
        const __hip_bfloat16* qvp =
            Qv + (tokbase + i0 + c16) * 1024 + headoff + quad * 8;
        const bf16x8 a0 = ldg8(qvp);
        const bf16x8 a1 = ldg8(qvp + 32);
        for (int t = 0; t < 16; ++t) {
            const int l0 = wv * 256 + t * 16;
            const float* rp =
                Pos + (tokbase + l0 + c16) * 1024 + headoff + quad * 8;
            f32x4 c = (f32x4){0.f, 0.f, 0.f, 0.f};
            c = MFMA16(a0, ldg8cvt(rp), c);
            c = MFMA16(a1, ldg8cvt(rp + 32), c);
            const int l = l0 + c16;
            #pragma unroll
            for (int r = 0; r < 4; ++r) {
                const int jl = quad * 4 + r;
                const int j  = i0 + jl;
                const float val = c[r];
                if (l >= 1023 - j) Ls[lidx(jl, l + j - 1023)] = val;
                if (jl >= 1 && l <= 1022 - j) Ls[lidx(jl - 1, l + j + 1)] = val;
            }
        }
    }

    // extra bd_raw row j2 = i0+16 feeds out row 15 at c >= i0+17.
    {
        const int j2 = i0 + 16;
        if (j2 < 1024) {
            const __hip_bfloat16* q2 = Qv + (tokbase + j2) * 1024 + headoff;
            for (int c = i0 + 17 + tid; c < 1024; c += 256) {
                const int l = c - i0 - 17;
                const float* rp = Pos + (tokbase + l) * 1024 + headoff;
                float s = 0.f;
                for (int d = 0; d < 64; ++d)
                    s += __bfloat162float(q2[d]) * rp[d];
                Ls[lidx(15, c)] = s;
            }
        }
    }
    __syncthreads();

    // AC = (q+u)·k^T; fuse L = (L + ac) * SCALE.
    {
        const __hip_bfloat16* qup =
            Qu + (tokbase + i0 + c16) * 1024 + headoff + quad * 8;
        const bf16x8 a0 = ldg8(qup);
        const bf16x8 a1 = ldg8(qup + 32);
        for (int t = 0; t < 16; ++t) {
            const int c0 = wv * 256 + t * 16;
            const __hip_bfloat16* kp =
                Kb + (tokbase + c0 + c16) * 1024 + headoff + quad * 8;
            f32x4 c = (f32x4){0.f, 0.f, 0.f, 0.f};
            c = MFMA16(a0, ldg8(kp), c);
            c = MFMA16(a1, ldg8(kp + 32), c);
            const int cc = c0 + c16;
            #pragma unroll
            for (int r = 0; r < 4; ++r) {
                const int il = quad * 4 + r;
                const int idx = lidx(il, cc);
                Ls[idx] = (Ls[idx] + c[r]) * 0.03125f;
            }
        }
    }
    __syncthreads();

    // row softmax in place.
    for (int rr = 0; rr < 4; ++rr) {
        const int row = wv * 4 + rr;
        float x[16];
        float m = -3.4e38f;
        #pragma unroll
        for (int k = 0; k < 16; ++k) {
            x[k] = Ls[lidx(row, k * 64 + lane)];
            m = fmaxf(m, x[k]);
        }
        #pragma unroll
        for (int off = 32; off > 0; off >>= 1) m = fmaxf(m, __shfl_xor(m, off));
        float s = 0.f;
        #pragma unroll
        for (int k = 0; k < 16; ++k) { x[k] = __expf(x[k] - m); s += x[k]; }
        #pragma unroll
        for (int off = 32; off > 0; off >>= 1) s += __shfl_xor(s, off);
        const float rinv = 1.f / s;
        #pragma unroll
        for (int k = 0; k < 16; ++k) Ls[lidx(row, k * 64 + lane)] = x[k] * rinv;
    }
    __syncthreads();

    // O_tile = P @ V.
    {
        const int d0 = wv * 16;
        const __hip_bfloat16* vp =
            Vt + ((size_t)bh * 64 + d0 + c16) * 1024 + quad * 8;
        f32x4 acc = (f32x4){0.f, 0.f, 0.f, 0.f};
        for (int kk = 0; kk < 1024; kk += 32) {
            const f32x4 f0 = *(const f32x4*)&Ls[lidx(c16, kk + quad * 8)];
            const f32x4 f1 = *(const f32x4*)&Ls[lidx(c16, kk + quad * 8 + 4)];
            bf16x8 a;
            a[0] = f2b(f0[0]); a[1] = f2b(f0[1]); a[2] = f2b(f0[2]); a[3] = f2b(f0[3]);
            a[4] = f2b(f1[0]); a[5] = f2b(f1[1]); a[6] = f2b(f1[2]); a[7] = f2b(f1[3]);
            acc = MFMA16(a, ldg8(vp + kk), acc);
        }
        #pragma unroll
        for (int r = 0; r < 4; ++r) {
            const int i = i0 + quad * 4 + r;
            const int d = d0 + c16;
            O[(tokbase + i) * 1024 + headoff + d] = __float2bfloat16(acc[r]);
        }
    }
}

// ---------------------------------------------------------------------------
extern "C" void kernel_launch(void* const* d_in, const int* in_sizes, int n_in,
                              void* d_out, int out_size, void* d_ws, size_t ws_size,
                              hipStream_t stream)
{
    const float* x   = (const float*)d_in[0];
    const float* u   = (const float*)d_in[1];
    const float* v   = (const float*)d_in[2];
    const float* pos = (const float*)d_in[3];
    const float* Wq  = (const float*)d_in[4];
    const float* bq  = (const float*)d_in[5];
    const float* Wk  = (const float*)d_in[6];
    const float* bk  = (const float*)d_in[7];
    const float* Wv  = (const float*)d_in[8];
    const float* bv  = (const float*)d_in[9];
    const float* Wc  = (const float*)d_in[10];
    const float* bc  = (const float*)d_in[11];

    const size_t MB = (size_t)1 << 20;
    char* ws = (char*)d_ws;
    __hip_bfloat16* Qu    = (__hip_bfloat16*)(ws + 0 * MB);
    __hip_bfloat16* Qv    = (__hip_bfloat16*)(ws + 8 * MB);
    __hip_bfloat16* Kb    = (__hip_bfloat16*)(ws + 16 * MB);
    __hip_bfloat16* Vt    = (__hip_bfloat16*)(ws + 24 * MB);
    __hip_bfloat16* xb    = (__hip_bfloat16*)(ws + 32 * MB);  // aliased w/ O
    __hip_bfloat16* O     = (__hip_bfloat16*)(ws + 32 * MB);  // x dead after QKV
    __hip_bfloat16* Wqkvb = (__hip_bfloat16*)(ws + 40 * MB);
    __hip_bfloat16* Wcb   = (__hip_bfloat16*)(ws + 46 * MB);

    cvt_kernel<<<4096, 256, 0, stream>>>(x, Wq, Wk, Wv, Wc, xb, Wqkvb, Wcb);

    gemm_lds<0><<<dim3(24, 32), dim3(256), 0, stream>>>(
        xb, Wqkvb, bq, bk, bv, u, v, Qu, Qv, Kb, Vt, nullptr, nullptr);

    attn_kernel<<<dim3(64, 64), dim3(256), 0, stream>>>(Qu, Qv, Kb, pos, Vt, O);

    gemm_lds<1><<<dim3(8, 32), dim3(256), 0, stream>>>(
        O, Wcb, nullptr, nullptr, nullptr, nullptr, nullptr,
        nullptr, nullptr, nullptr, nullptr, (float*)d_out, bc);
}

// Round 4
// 416.940 us; speedup vs baseline: 2.3930x; 1.2195x over previous
//
#include <hip/hip_runtime.h>
#include <hip/hip_bf16.h>

// RelAttention (Transformer-XL style) on MI355X.
// fp32 in/out; internal bf16 MFMA w/ fp32 accum.
// B=4, S=1024, D=1024, H=16, DH=64, BH=64. SCALE = 1/32.
//
// Pipeline: cvt (fp32->bf16: x, pos, weights) -> fused QKV GEMM (m97-style
// LDS staging) -> fused rel-attention (512 thr, 16 waves/CU) -> final GEMM.

typedef __bf16 bf16x8 __attribute__((ext_vector_type(8)));
typedef float  f32x4  __attribute__((ext_vector_type(4)));
typedef unsigned short u16x4 __attribute__((ext_vector_type(4)));

struct alignas(16) U128 { unsigned long long lo, hi; };

__device__ __forceinline__ bf16x8 ldg8(const __hip_bfloat16* p) {
    U128 u = *reinterpret_cast<const U128*>(p);
    return __builtin_bit_cast(bf16x8, u);
}

__device__ __forceinline__ __bf16 f2b(float f) {
    __hip_bfloat16 h = __float2bfloat16(f);
    return __builtin_bit_cast(__bf16, h);
}
__device__ __forceinline__ unsigned short f2bu(float f) {
    __hip_bfloat16 h = __float2bfloat16(f);
    return __builtin_bit_cast(unsigned short, h);
}
__device__ __forceinline__ float b2f(__bf16 b) {
    __hip_bfloat16 h = __builtin_bit_cast(__hip_bfloat16, b);
    return __bfloat162float(h);
}

__device__ __forceinline__ bf16x8 ldg8cvt(const float* p) {
    f32x4 a = *reinterpret_cast<const f32x4*>(p);
    f32x4 b = *reinterpret_cast<const f32x4*>(p + 4);
    bf16x8 r;
    r[0] = f2b(a[0]); r[1] = f2b(a[1]); r[2] = f2b(a[2]); r[3] = f2b(a[3]);
    r[4] = f2b(b[0]); r[5] = f2b(b[1]); r[6] = f2b(b[2]); r[7] = f2b(b[3]);
    return r;
}

#define MFMA16(a, b, c) __builtin_amdgcn_mfma_f32_16x16x32_bf16((a), (b), (c), 0, 0, 0)

__device__ __forceinline__ void gll16(const __hip_bfloat16* g, void* lds_wave_base) {
    __builtin_amdgcn_global_load_lds(
        (const __attribute__((address_space(1))) void*)g,
        (__attribute__((address_space(3))) void*)lds_wave_base,
        16, 0, 0);
}

// ---------------------------------------------------------------------------
// fp32 -> bf16: x(4M), pos(4M), Wq/Wk/Wv(3M stacked), Wc(1M) = 12M elems.
// ---------------------------------------------------------------------------
__global__ __launch_bounds__(256) void cvt_kernel(
    const float* __restrict__ x,  const float* __restrict__ pos,
    const float* __restrict__ wq, const float* __restrict__ wk,
    const float* __restrict__ wv, const float* __restrict__ wc,
    __hip_bfloat16* __restrict__ xb, __hip_bfloat16* __restrict__ posb,
    __hip_bfloat16* __restrict__ wqkvb, __hip_bfloat16* __restrict__ wcb)
{
    const size_t base = ((size_t)blockIdx.x * 256 + threadIdx.x) * 8;
    const size_t M1 = (size_t)1 << 20;
    const float* src; __hip_bfloat16* dst; size_t o;
    if (base < 4*M1)        { src = x;   dst = xb;           o = base; }
    else if (base < 8*M1)   { src = pos; dst = posb;         o = base - 4*M1; }
    else if (base < 9*M1)   { src = wq;  dst = wqkvb;        o = base - 8*M1; }
    else if (base < 10*M1)  { src = wk;  dst = wqkvb + M1;   o = base - 9*M1; }
    else if (base < 11*M1)  { src = wv;  dst = wqkvb + 2*M1; o = base - 10*M1; }
    else                    { src = wc;  dst = wcb;          o = base - 11*M1; }
    *(bf16x8*)(dst + o) = ldg8cvt(src + o);
}

// ---------------------------------------------------------------------------
// m97-style GEMM: C[m][n] = sum_k A[m][k]*Bm[n][k] (+ epilogue), K=1024.
// MODE 0 (QKV, Bm=[3072][1024]): n<1024 -> Qu = C+bq+u; <2048 -> Kb = C+bk;
//                                else Vt head-transposed = C+bv.
// MODE 1 (final): dout fp32 = C + bc[n].
// ---------------------------------------------------------------------------
template <int MODE>
__global__ __launch_bounds__(256) void gemm_lds(
    const __hip_bfloat16* __restrict__ A,
    const __hip_bfloat16* __restrict__ Bm,
    const float* __restrict__ bq, const float* __restrict__ bk,
    const float* __restrict__ bv, const float* __restrict__ u,
    __hip_bfloat16* __restrict__ Qu,
    __hip_bfloat16* __restrict__ Kb, __hip_bfloat16* __restrict__ Vt,
    float* __restrict__ dout, const float* __restrict__ bc)
{
    __shared__ __hip_bfloat16 As[128 * 32];
    __shared__ __hip_bfloat16 Bs[128 * 32];

    const int tid  = threadIdx.x;
    const int lane = tid & 63, w = tid >> 6;
    const int quad = lane >> 4, c16 = lane & 15;
    const int wm = w >> 1, wn = w & 1;
    const int m0 = blockIdx.y * 128;
    const int n0 = blockIdx.x * 128;

    const int srow = w * 16 + (lane >> 2);
    const int scol = (lane & 3) * 8;
    const __hip_bfloat16* gA0 = A  + (size_t)(m0 + srow) * 1024 + scol;
    const __hip_bfloat16* gA1 = gA0 + (size_t)64 * 1024;
    const __hip_bfloat16* gB0 = Bm + (size_t)(n0 + srow) * 1024 + scol;
    const __hip_bfloat16* gB1 = gB0 + (size_t)64 * 1024;
    char* ldsA0 = (char*)As + (w << 10);
    char* ldsA1 = ldsA0 + 4096;
    char* ldsB0 = (char*)Bs + (w << 10);
    char* ldsB1 = ldsB0 + 4096;

    f32x4 acc[4][4] = {};

    for (int k0 = 0; k0 < 1024; k0 += 32) {
        gll16(gA0 + k0, ldsA0);
        gll16(gA1 + k0, ldsA1);
        gll16(gB0 + k0, ldsB0);
        gll16(gB1 + k0, ldsB1);
        __syncthreads();

        bf16x8 af[4], bfr[4];
        #pragma unroll
        for (int i = 0; i < 4; ++i) {
            af[i]  = *(const bf16x8*)&As[(wm * 64 + i * 16 + c16) * 32 + quad * 8];
            bfr[i] = *(const bf16x8*)&Bs[(wn * 64 + i * 16 + c16) * 32 + quad * 8];
        }
        #pragma unroll
        for (int mi = 0; mi < 4; ++mi)
            #pragma unroll
            for (int ni = 0; ni < 4; ++ni)
                acc[mi][ni] = MFMA16(af[mi], bfr[ni], acc[mi][ni]);
        __syncthreads();
    }

    #pragma unroll
    for (int mi = 0; mi < 4; ++mi) {
        #pragma unroll
        for (int ni = 0; ni < 4; ++ni) {
            const int m = m0 + wm * 64 + mi * 16 + quad * 4;  // +r
            const int n = n0 + wn * 64 + ni * 16 + c16;
            if (MODE == 0) {
                if (n < 1024) {
                    const float b0 = bq[n] + u[n & 63];
                    #pragma unroll
                    for (int r = 0; r < 4; ++r)
                        Qu[(size_t)(m + r) * 1024 + n] =
                            __float2bfloat16(acc[mi][ni][r] + b0);
                } else if (n < 2048) {
                    const int nn = n - 1024;
                    const float b0 = bk[nn];
                    #pragma unroll
                    for (int r = 0; r < 4; ++r)
                        Kb[(size_t)(m + r) * 1024 + nn] =
                            __float2bfloat16(acc[mi][ni][r] + b0);
                } else {
                    const int nn = n - 2048;
                    const float b0 = bv[nn];
                    const int d = nn & 63, hh = nn >> 6;
                    const int bb = m >> 10, s = m & 1023;
                    u16x4 pk;
                    #pragma unroll
                    for (int r = 0; r < 4; ++r)
                        pk[r] = f2bu(acc[mi][ni][r] + b0);
                    *(u16x4*)&Vt[(((size_t)(bb * 16 + hh) * 64 + d) << 10) + s] = pk;
                }
            } else {
                const float b0 = bc[n];
                #pragma unroll
                for (int r = 0; r < 4; ++r)
                    dout[(size_t)(m + r) * 1024 + n] = acc[mi][ni][r] + b0;
            }
        }
    }
}

// ---------------------------------------------------------------------------
// Fused relative attention, 512 threads (8 waves), 16-row tile, 64 KiB LDS.
// Qv is derived in-register: (q+v) = Qu + (v-u).
// ---------------------------------------------------------------------------
__device__ __forceinline__ int lidx(int row, int c) {
    return (row << 10) + ((((c >> 2) ^ row) << 2) | (c & 3));
}

__global__ __launch_bounds__(512) void attn_kernel(
    const __hip_bfloat16* __restrict__ Qu,   // [4096][1024] (q+bq+u)
    const __hip_bfloat16* __restrict__ Kb,   // [4096][1024]
    const __hip_bfloat16* __restrict__ Posb, // [4096][1024] bf16 pos
    const __hip_bfloat16* __restrict__ Vt,   // [bh*64+d][s]
    const float* __restrict__ uvec, const float* __restrict__ vvec,
    __hip_bfloat16* __restrict__ O)          // [4096][1024]
{
    __shared__ float Ls[16 * 1024];
    __shared__ float q2s[64];

    const int tid  = threadIdx.x;
    const int lane = tid & 63, w = tid >> 6;   // w in [0,8)
    const int quad = lane >> 4, c16 = lane & 15;
    const int i0 = blockIdx.x * 16;
    const int bh = blockIdx.y;
    const int b = bh >> 4, h = bh & 15;
    const size_t headoff = (size_t)h * 64;
    const size_t tokbase = (size_t)b * 1024;
    const int j2 = i0 + 16;

    // q2s = (q+v) row j2 (fp32), for phase 3.
    if (tid < 64) {
        float val = 0.f;
        if (j2 < 1024)
            val = b2f(__builtin_bit_cast(__bf16,
                      Qu[(tokbase + j2) * 1024 + headoff + tid])) +
                  (vvec[tid] - uvec[tid]);
        q2s[tid] = val;
    }
    __syncthreads();

    // Phase 1: the rel-shift leaves exactly one zero per row, at c = i+1.
    if (tid < 16) {
        const int i = i0 + tid;
        if (i + 1 < 1024) Ls[lidx(tid, i + 1)] = 0.f;
    }

    // A-fragments: au = (q+u) rows, a = (q+v) rows (derived).
    const __hip_bfloat16* qup =
        Qu + (tokbase + i0 + c16) * 1024 + headoff + quad * 8;
    const bf16x8 au0 = ldg8(qup);
    const bf16x8 au1 = ldg8(qup + 32);
    bf16x8 a0, a1;
    #pragma unroll
    for (int j = 0; j < 8; ++j) {
        const int d = quad * 8 + j;
        a0[j] = f2b(b2f(au0[j]) + (vvec[d] - uvec[d]));
        a1[j] = f2b(b2f(au1[j]) + (vvec[d + 32] - uvec[d + 32]));
    }

    // Phase 2: BD_raw = (q+v)·r^T, scattered through the rel-shift.
    // bd_raw row j, col l -> out row j   at c = l+j-1023  (l >= 1023-j)
    //                     -> out row j-1 at c = l+j+1     (l <= 1022-j)
    for (int t = 0; t < 8; ++t) {
        const int l0 = w * 128 + t * 16;
        const __hip_bfloat16* rp =
            Posb + (tokbase + l0 + c16) * 1024 + headoff + quad * 8;
        f32x4 c = (f32x4){0.f, 0.f, 0.f, 0.f};
        c = MFMA16(a0, ldg8(rp), c);
        c = MFMA16(a1, ldg8(rp + 32), c);
        const int l = l0 + c16;
        #pragma unroll
        for (int r = 0; r < 4; ++r) {
            const int jl = quad * 4 + r;
            const int j  = i0 + jl;
            const float val = c[r];
            if (l >= 1023 - j) Ls[lidx(jl, l + j - 1023)] = val;
            if (jl >= 1 && l <= 1022 - j) Ls[lidx(jl - 1, l + j + 1)] = val;
        }
    }

    // Phase 3: extra bd_raw row j2 feeds out row 15 at c >= i0+17.
    if (j2 < 1024) {
        for (int c = i0 + 17 + tid; c < 1024; c += 512) {
            const int l = c - i0 - 17;
            const __hip_bfloat16* rp = Posb + (tokbase + l) * 1024 + headoff;
            float s = 0.f;
            #pragma unroll 8
            for (int d = 0; d < 64; ++d)
                s += q2s[d] * b2f(__builtin_bit_cast(__bf16, rp[d]));
            Ls[lidx(15, c)] = s;
        }
    }
    __syncthreads();

    // Phase 4: AC = (q+u)·k^T; fuse L = (L + ac) * SCALE.
    for (int t = 0; t < 8; ++t) {
        const int c0 = w * 128 + t * 16;
        const __hip_bfloat16* kp =
            Kb + (tokbase + c0 + c16) * 1024 + headoff + quad * 8;
        f32x4 c = (f32x4){0.f, 0.f, 0.f, 0.f};
        c = MFMA16(au0, ldg8(kp), c);
        c = MFMA16(au1, ldg8(kp + 32), c);
        const int cc = c0 + c16;
        #pragma unroll
        for (int r = 0; r < 4; ++r) {
            const int il = quad * 4 + r;
            const int idx = lidx(il, cc);
            Ls[idx] = (Ls[idx] + c[r]) * 0.03125f;
        }
    }
    __syncthreads();

    // Phase 5: row softmax in place (wave w owns rows 2w, 2w+1).
    for (int rr = 0; rr < 2; ++rr) {
        const int row = w * 2 + rr;
        float x[16];
        float m = -3.4e38f;
        #pragma unroll
        for (int k = 0; k < 16; ++k) {
            x[k] = Ls[lidx(row, k * 64 + lane)];
            m = fmaxf(m, x[k]);
        }
        #pragma unroll
        for (int off = 32; off > 0; off >>= 1) m = fmaxf(m, __shfl_xor(m, off));
        float s = 0.f;
        #pragma unroll
        for (int k = 0; k < 16; ++k) { x[k] = __expf(x[k] - m); s += x[k]; }
        #pragma unroll
        for (int off = 32; off > 0; off >>= 1) s += __shfl_xor(s, off);
        const float rinv = 1.f / s;
        #pragma unroll
        for (int k = 0; k < 16; ++k) Ls[lidx(row, k * 64 + lane)] = x[k] * rinv;
    }
    __syncthreads();

    // Phase 6: O_tile = P @ V. Wave w: d-tile d0=(w&3)*16, k-half kh=w>>2.
    {
        const int d0 = (w & 3) * 16;
        const int kh = w >> 2;
        const __hip_bfloat16* vp =
            Vt + ((size_t)bh * 64 + d0 + c16) * 1024 + quad * 8;
        f32x4 acc = (f32x4){0.f, 0.f, 0.f, 0.f};
        for (int kk = kh * 512; kk < kh * 512 + 512; kk += 32) {
            const f32x4 f0 = *(const f32x4*)&Ls[lidx(c16, kk + quad * 8)];
            const f32x4 f1 = *(const f32x4*)&Ls[lidx(c16, kk + quad * 8 + 4)];
            bf16x8 a;
            a[0] = f2b(f0[0]); a[1] = f2b(f0[1]); a[2] = f2b(f0[2]); a[3] = f2b(f0[3]);
            a[4] = f2b(f1[0]); a[5] = f2b(f1[1]); a[6] = f2b(f1[2]); a[7] = f2b(f1[3]);
            acc = MFMA16(a, ldg8(vp + kk), acc);
        }
        __syncthreads();   // all P reads done; logits LDS now reusable
        const int sbase = (w & 3) * 256;
        if (kh == 1) {
            #pragma unroll
            for (int r = 0; r < 4; ++r)
                Ls[sbase + (quad * 4 + r) * 16 + c16] = acc[r];
        }
        __syncthreads();
        if (kh == 0) {
            #pragma unroll
            for (int r = 0; r < 4; ++r) {
                const float val = acc[r] + Ls[sbase + (quad * 4 + r) * 16 + c16];
                const int i = i0 + quad * 4 + r;
                const int d = d0 + c16;
                O[(tokbase + i) * 1024 + headoff + d] = __float2bfloat16(val);
            }
        }
    }
}

// ---------------------------------------------------------------------------
extern "C" void kernel_launch(void* const* d_in, const int* in_sizes, int n_in,
                              void* d_out, int out_size, void* d_ws, size_t ws_size,
                              hipStream_t stream)
{
    const float* x   = (const float*)d_in[0];
    const float* u   = (const float*)d_in[1];
    const float* v   = (const float*)d_in[2];
    const float* pos = (const float*)d_in[3];
    const float* Wq  = (const float*)d_in[4];
    const float* bq  = (const float*)d_in[5];
    const float* Wk  = (const float*)d_in[6];
    const float* bk  = (const float*)d_in[7];
    const float* Wv  = (const float*)d_in[8];
    const float* bv  = (const float*)d_in[9];
    const float* Wc  = (const float*)d_in[10];
    const float* bc  = (const float*)d_in[11];

    const size_t MB = (size_t)1 << 20;
    char* ws = (char*)d_ws;
    __hip_bfloat16* Qu    = (__hip_bfloat16*)(ws + 0 * MB);
    __hip_bfloat16* Kb    = (__hip_bfloat16*)(ws + 8 * MB);
    __hip_bfloat16* Vt    = (__hip_bfloat16*)(ws + 16 * MB);
    __hip_bfloat16* xb    = (__hip_bfloat16*)(ws + 24 * MB);  // aliased w/ O
    __hip_bfloat16* O     = (__hip_bfloat16*)(ws + 24 * MB);  // x dead after QKV
    __hip_bfloat16* Posb  = (__hip_bfloat16*)(ws + 32 * MB);
    __hip_bfloat16* Wqkvb = (__hip_bfloat16*)(ws + 40 * MB);
    __hip_bfloat16* Wcb   = (__hip_bfloat16*)(ws + 46 * MB);

    cvt_kernel<<<6144, 256, 0, stream>>>(x, pos, Wq, Wk, Wv, Wc,
                                         xb, Posb, Wqkvb, Wcb);

    gemm_lds<0><<<dim3(24, 32), dim3(256), 0, stream>>>(
        xb, Wqkvb, bq, bk, bv, u, Qu, Kb, Vt, nullptr, nullptr);

    attn_kernel<<<dim3(64, 64), dim3(512), 0, stream>>>(
        Qu, Kb, Posb, Vt, u, v, O);

    gemm_lds<1><<<dim3(8, 32), dim3(256), 0, stream>>>(
        O, Wcb, nullptr, nullptr, nullptr, nullptr,
        nullptr, nullptr, nullptr, (float*)d_out, bc);
}